// Round 3
// baseline (267.386 us; speedup 1.0000x reference)
//
#include <hip/hip_runtime.h>

typedef _Float16 f16;
typedef f16  f16x8 __attribute__((ext_vector_type(8)));
typedef f16  f16x4 __attribute__((ext_vector_type(4)));
typedef float f32x4 __attribute__((ext_vector_type(4)));

#define MFMA16(a,b,c) __builtin_amdgcn_mfma_f32_16x16x32_f16((a),(b),(c),0,0,0)

static constexpr int Tq   = 2048;  // sequence length
static constexpr int Cdim = 1024;  // model dim
// heads = 16, d_head = 64, batch = 2 (hardcoded below)

// ---------------- x (f32) -> f16 ----------------
__global__ __launch_bounds__(256) void k_cvt_x(const float* __restrict__ x, f16* __restrict__ xh)
{
    int i = blockIdx.x * 256 + threadIdx.x;
    f32x4 v = ((const f32x4*)x)[i];
    f16x4 o; o[0] = (f16)v[0]; o[1] = (f16)v[1]; o[2] = (f16)v[2]; o[3] = (f16)v[3];
    ((f16x4*)xh)[i] = o;
}

// ------------- W (K x N, f32) -> WT (N x K, f16) -------------
__global__ __launch_bounds__(256) void k_trans(const float* __restrict__ W, f16* __restrict__ WT,
                                               int K, int N)
{
    __shared__ float t[64][65];
    int n0 = blockIdx.x * 64, k0 = blockIdx.y * 64;
    int tid = threadIdx.x;
    int lr = tid >> 6, lc = tid & 63;
    #pragma unroll 4
    for (int i = 0; i < 16; i++) {
        int kl = lr * 16 + i;
        t[kl][lc] = W[(size_t)(k0 + kl) * N + n0 + lc];
    }
    __syncthreads();
    #pragma unroll 4
    for (int i = 0; i < 16; i++) {
        int nl = lr * 16 + i;
        WT[(size_t)(n0 + nl) * K + k0 + lc] = (f16)t[lc][nl];
    }
}

// ------------- GEMM: C = A(MxK) * BT(NxK)^T + bias -------------
// EPI 0: write f32 C.  EPI 1: route QKV into Qc/Kc (bh,t,d) and Vt (bh,d,t).
template<int EPI>
__global__ __launch_bounds__(256) void k_gemm(
    const f16* __restrict__ A, const f16* __restrict__ BT, const float* __restrict__ bias,
    float* __restrict__ Cf, f16* __restrict__ Qc, f16* __restrict__ Kc, f16* __restrict__ Vt,
    int N, int K)
{
    __shared__ __align__(16) f16 As[128][64];
    __shared__ __align__(16) f16 Bs[128][64];
    const int tid = threadIdx.x;
    const int lane = tid & 63, wv = tid >> 6;
    const int l16 = lane & 15, lhi = lane >> 4;
    const int wr = wv >> 1, wc = wv & 1;
    const int bm = blockIdx.y * 128, bn = blockIdx.x * 128;

    f32x4 acc[4][4] = {};

    for (int kt = 0; kt < K; kt += 64) {
        #pragma unroll
        for (int r = 0; r < 4; r++) {
            int c   = tid + r * 256;
            int row = c >> 3, ch = c & 7;
            int pch = ch ^ (row & 7);
            *(f16x8*)&As[row][pch * 8] = *(const f16x8*)(A  + (size_t)(bm + row) * K + kt + ch * 8);
            *(f16x8*)&Bs[row][pch * 8] = *(const f16x8*)(BT + (size_t)(bn + row) * K + kt + ch * 8);
        }
        __syncthreads();
        #pragma unroll
        for (int kk = 0; kk < 2; kk++) {
            f16x8 af[4], bfr[4];
            #pragma unroll
            for (int i = 0; i < 4; i++) {
                int ra = wr * 64 + i * 16 + l16;
                af[i]  = *(const f16x8*)&As[ra][((kk * 4 + lhi) ^ (ra & 7)) * 8];
                int rb = wc * 64 + i * 16 + l16;
                bfr[i] = *(const f16x8*)&Bs[rb][((kk * 4 + lhi) ^ (rb & 7)) * 8];
            }
            #pragma unroll
            for (int i = 0; i < 4; i++)
                #pragma unroll
                for (int j = 0; j < 4; j++)
                    acc[i][j] = MFMA16(af[i], bfr[j], acc[i][j]);
        }
        __syncthreads();
    }

    #pragma unroll
    for (int i = 0; i < 4; i++) {
        int row0 = bm + wr * 64 + i * 16 + lhi * 4;   // +r
        #pragma unroll
        for (int j = 0; j < 4; j++) {
            int col = bn + wc * 64 + j * 16 + l16;
            float bv = bias[col];
            if (EPI == 0) {
                #pragma unroll
                for (int r = 0; r < 4; r++)
                    Cf[(size_t)(row0 + r) * N + col] = acc[i][j][r] + bv;
            } else {
                int b_ = row0 >> 11;          // T = 2048
                int t0 = row0 & 2047;
                int s  = col >> 10;           // 0=Q 1=K 2=V
                int h  = (col >> 6) & 15;
                int d  = col & 63;
                int bh = b_ * 16 + h;
                if (s < 2) {
                    f16* dst = (s == 0 ? Qc : Kc);
                    #pragma unroll
                    for (int r = 0; r < 4; r++)
                        dst[((size_t)bh * Tq + t0 + r) * 64 + d] = (f16)(acc[i][j][r] + bv);
                } else {
                    f16x4 p;
                    #pragma unroll
                    for (int r = 0; r < 4; r++) p[r] = (f16)(acc[i][j][r] + bv);
                    *(f16x4*)&Vt[((size_t)bh * 64 + d) * Tq + t0] = p;
                }
            }
        }
    }
}

// ------------- attention: softmax(Q K^T) V / 8 -> Yc (f16, [b*T][C]) -------------
__global__ __launch_bounds__(256) void k_attn(
    const f16* __restrict__ Qc, const f16* __restrict__ Kc, const f16* __restrict__ Vt,
    f16* __restrict__ Yc)
{
    __shared__ __align__(16) f16 Ks[64][64];
    __shared__ __align__(16) f16 Vs[64][64];
    __shared__ __align__(16) f16 Ps[4][16][64];

    const int tid = threadIdx.x;
    const int lane = tid & 63, wv = tid >> 6;
    const int l16 = lane & 15, lhi = lane >> 4;
    const int bh = blockIdx.y;
    const int q0 = blockIdx.x * 64;

    const f16* Qh = Qc + (size_t)bh * Tq * 64;
    const f16* Kh = Kc + (size_t)bh * Tq * 64;
    const f16* Vh = Vt + (size_t)bh * 64 * Tq;

    // Q fragments (A operand): row = q0 + wv*16 + l16, k = kk*32 + lhi*8
    f16x8 qf[2];
    {
        int qrow = q0 + wv * 16 + l16;
        #pragma unroll
        for (int kk = 0; kk < 2; kk++)
            qf[kk] = *(const f16x8*)(Qh + (size_t)qrow * 64 + kk * 32 + lhi * 8);
    }

    f32x4 o[4] = {};
    float m[4], l[4];
    #pragma unroll
    for (int r = 0; r < 4; r++) { m[r] = -1e30f; l[r] = 0.0f; }

    for (int kt = 0; kt < Tq; kt += 64) {
        // stage K tile: 64 keys x 64 d
        #pragma unroll
        for (int r = 0; r < 2; r++) {
            int c = tid + r * 256;
            int row = c >> 3, ch = c & 7;
            int pch = ch ^ (row & 7);
            *(f16x8*)&Ks[row][pch * 8] = *(const f16x8*)(Kh + (size_t)(kt + row) * 64 + ch * 8);
        }
        // stage V tile (transposed layout): 64 d-rows x 64 keys
        #pragma unroll
        for (int r = 0; r < 2; r++) {
            int c = tid + r * 256;
            int row = c >> 3, ch = c & 7;
            int pch = ch ^ (row & 7);
            *(f16x8*)&Vs[row][pch * 8] = *(const f16x8*)(Vh + (size_t)row * Tq + kt + ch * 8);
        }
        __syncthreads();

        // S = Q K^T  (4 key sub-tiles of 16)
        f32x4 s[4];
        #pragma unroll
        for (int ck = 0; ck < 4; ck++) {
            f32x4 t = {};
            #pragma unroll
            for (int kk = 0; kk < 2; kk++) {
                int row = ck * 16 + l16;
                f16x8 kf = *(const f16x8*)&Ks[row][((kk * 4 + lhi) ^ (row & 7)) * 8];
                t = MFMA16(qf[kk], kf, t);
            }
            s[ck] = t;
        }

        // online softmax (rows r = lhi*4 + r, key = ck*16 + l16; reduce over 16-lane group)
        float mn[4], sc[4];
        #pragma unroll
        for (int r = 0; r < 4; r++) {
            float tm = fmaxf(fmaxf(s[0][r], s[1][r]), fmaxf(s[2][r], s[3][r]));
            #pragma unroll
            for (int off = 1; off < 16; off <<= 1)
                tm = fmaxf(tm, __shfl_xor(tm, off, 16));
            mn[r] = fmaxf(m[r], tm);
            sc[r] = __expf(m[r] - mn[r]);
            m[r] = mn[r];
        }
        float ps[4][4];
        #pragma unroll
        for (int ck = 0; ck < 4; ck++)
            #pragma unroll
            for (int r = 0; r < 4; r++)
                ps[ck][r] = __expf(s[ck][r] - mn[r]);
        #pragma unroll
        for (int r = 0; r < 4; r++) {
            float su = ps[0][r] + ps[1][r] + ps[2][r] + ps[3][r];
            #pragma unroll
            for (int off = 1; off < 16; off <<= 1)
                su += __shfl_xor(su, off, 16);
            l[r] = l[r] * sc[r] + su;
        }
        #pragma unroll
        for (int ct = 0; ct < 4; ct++)
            #pragma unroll
            for (int r = 0; r < 4; r++)
                o[ct][r] *= sc[r];

        // write P (f16) into per-wave LDS, swizzled for A-frag reads
        #pragma unroll
        for (int ck = 0; ck < 4; ck++)
            #pragma unroll
            for (int r = 0; r < 4; r++) {
                int prow = lhi * 4 + r;
                int pcol = ck * 16 + l16;
                Ps[wv][prow][(((pcol >> 3) ^ (prow & 7)) << 3) | (pcol & 7)] = (f16)ps[ck][r];
            }
        asm volatile("s_waitcnt lgkmcnt(0)" ::: "memory");

        // PV
        f16x8 pa[2];
        #pragma unroll
        for (int kk2 = 0; kk2 < 2; kk2++) {
            int pr = l16;
            pa[kk2] = *(const f16x8*)&Ps[wv][pr][((kk2 * 4 + lhi) ^ (pr & 7)) * 8];
        }
        #pragma unroll
        for (int ct = 0; ct < 4; ct++) {
            int d = ct * 16 + l16;
            #pragma unroll
            for (int kk2 = 0; kk2 < 2; kk2++) {
                f16x8 vf = *(const f16x8*)&Vs[d][((kk2 * 4 + lhi) ^ (d & 7)) * 8];
                o[ct] = MFMA16(pa[kk2], vf, o[ct]);
            }
        }
        __syncthreads();
    }

    // epilogue: y = o / l / 8, write f16 Yc[b*T + t][h*64 + d]
    const int b_ = bh >> 4, h_ = bh & 15;
    #pragma unroll
    for (int r = 0; r < 4; r++) {
        float inv = 1.0f / (l[r] * 8.0f);
        int trow = q0 + wv * 16 + lhi * 4 + r;
        size_t rb = (size_t)(b_ * Tq + trow) * Cdim;
        #pragma unroll
        for (int ct = 0; ct < 4; ct++) {
            int cc = h_ * 64 + ct * 16 + l16;
            Yc[rb + cc] = (f16)(o[ct][r] * inv);
        }
    }
}

extern "C" void kernel_launch(void* const* d_in, const int* in_sizes, int n_in,
                              void* d_out, int out_size, void* d_ws, size_t ws_size,
                              hipStream_t stream)
{
    (void)in_sizes; (void)n_in; (void)out_size; (void)ws_size;
    const float* x  = (const float*)d_in[0];
    const float* Wa = (const float*)d_in[1];
    const float* ba = (const float*)d_in[2];
    const float* Wp = (const float*)d_in[3];
    const float* bp = (const float*)d_in[4];
    float* out = (float*)d_out;

    char* ws = (char*)d_ws;               // needs 48 MB
    f16* Xh  = (f16*)(ws);                //  8 MB  [4096][1024]
    f16* WaT = (f16*)(ws + (8u  << 20));  //  6 MB  [3072][1024]
    f16* WpT = (f16*)(ws + (14u << 20));  //  2 MB  [1024][1024]
    f16* Qc  = (f16*)(ws + (16u << 20));  //  8 MB  [32][2048][64]
    f16* Kc  = (f16*)(ws + (24u << 20));  //  8 MB  [32][2048][64]
    f16* Vt  = (f16*)(ws + (32u << 20));  //  8 MB  [32][64][2048]
    f16* Yc  = (f16*)(ws + (40u << 20));  //  8 MB  [4096][1024]

    k_cvt_x<<<4096, 256, 0, stream>>>(x, Xh);
    k_trans<<<dim3(48, 16), 256, 0, stream>>>(Wa, WaT, 1024, 3072);
    k_trans<<<dim3(16, 16), 256, 0, stream>>>(Wp, WpT, 1024, 1024);
    k_gemm<1><<<dim3(24, 32), 256, 0, stream>>>(Xh, WaT, ba, nullptr, Qc, Kc, Vt, 3072, 1024);
    k_attn<<<dim3(32, 32), 256, 0, stream>>>(Qc, Kc, Vt, Yc);
    k_gemm<0><<<dim3(8, 32), 256, 0, stream>>>(Yc, WpT, bp, out, nullptr, nullptr, nullptr, 1024, 1024);
}

// Round 5
// 217.139 us; speedup vs baseline: 1.2314x; 1.2314x over previous
//
#include <hip/hip_runtime.h>

typedef _Float16 f16;
typedef f16  f16x8 __attribute__((ext_vector_type(8)));
typedef f16  f16x4 __attribute__((ext_vector_type(4)));
typedef float f32x4 __attribute__((ext_vector_type(4)));
typedef int  i32x4 __attribute__((ext_vector_type(4)));

#define MFMA16(a,b,c) __builtin_amdgcn_mfma_f32_16x16x32_f16((a),(b),(c),0,0,0)
#define EXP2(x) __builtin_amdgcn_exp2f(x)
#define LOG2E 1.44269504089f

static constexpr int Tq   = 2048;  // sequence length
static constexpr int Cdim = 1024;  // model dim
// heads = 16, d_head = 64, batch = 2 (hardcoded below)

// ---------------- x (f32) -> f16 ----------------
__global__ __launch_bounds__(256) void k_cvt_x(const float* __restrict__ x, f16* __restrict__ xh)
{
    int i = blockIdx.x * 256 + threadIdx.x;
    f32x4 v = ((const f32x4*)x)[i];
    f16x4 o; o[0] = (f16)v[0]; o[1] = (f16)v[1]; o[2] = (f16)v[2]; o[3] = (f16)v[3];
    ((f16x4*)xh)[i] = o;
}

// ------------- W (K x N, f32) -> WT (N x K, f16) -------------
__global__ __launch_bounds__(256) void k_trans(const float* __restrict__ W, f16* __restrict__ WT,
                                               int K, int N)
{
    __shared__ float t[64][65];
    int n0 = blockIdx.x * 64, k0 = blockIdx.y * 64;
    int tid = threadIdx.x;
    int lr = tid >> 6, lc = tid & 63;
    #pragma unroll 4
    for (int i = 0; i < 16; i++) {
        int kl = lr * 16 + i;
        t[kl][lc] = W[(size_t)(k0 + kl) * N + n0 + lc];
    }
    __syncthreads();
    #pragma unroll 4
    for (int i = 0; i < 16; i++) {
        int nl = lr * 16 + i;
        WT[(size_t)(n0 + nl) * K + k0 + lc] = (f16)t[lc][nl];
    }
}

// ------------- GEMM: C = A(MxK) * BT(NxK)^T + bias -------------
// EPI 0: write f32 C.  EPI 1: route QKV into Qc/Kc (bh,t,d) and Vt (bh,d,t).
template<int EPI>
__global__ __launch_bounds__(256) void k_gemm(
    const f16* __restrict__ A, const f16* __restrict__ BT, const float* __restrict__ bias,
    float* __restrict__ Cf, f16* __restrict__ Qc, f16* __restrict__ Kc, f16* __restrict__ Vt,
    int N, int K)
{
    __shared__ __align__(16) f16 As[128][64];
    __shared__ __align__(16) f16 Bs[128][64];
    const int tid = threadIdx.x;
    const int lane = tid & 63, wv = tid >> 6;
    const int l16 = lane & 15, lhi = lane >> 4;
    const int wr = wv >> 1, wc = wv & 1;
    const int bm = blockIdx.y * 128, bn = blockIdx.x * 128;

    f32x4 acc[4][4] = {};

    for (int kt = 0; kt < K; kt += 64) {
        #pragma unroll
        for (int r = 0; r < 4; r++) {
            int c   = tid + r * 256;
            int row = c >> 3, ch = c & 7;
            int pch = ch ^ (row & 7);
            *(f16x8*)&As[row][pch * 8] = *(const f16x8*)(A  + (size_t)(bm + row) * K + kt + ch * 8);
            *(f16x8*)&Bs[row][pch * 8] = *(const f16x8*)(BT + (size_t)(bn + row) * K + kt + ch * 8);
        }
        __syncthreads();
        #pragma unroll
        for (int kk = 0; kk < 2; kk++) {
            f16x8 af[4], bfr[4];
            #pragma unroll
            for (int i = 0; i < 4; i++) {
                int ra = wr * 64 + i * 16 + l16;
                af[i]  = *(const f16x8*)&As[ra][((kk * 4 + lhi) ^ (ra & 7)) * 8];
                int rb = wc * 64 + i * 16 + l16;
                bfr[i] = *(const f16x8*)&Bs[rb][((kk * 4 + lhi) ^ (rb & 7)) * 8];
            }
            #pragma unroll
            for (int i = 0; i < 4; i++)
                #pragma unroll
                for (int j = 0; j < 4; j++)
                    acc[i][j] = MFMA16(af[i], bfr[j], acc[i][j]);
        }
        __syncthreads();
    }

    #pragma unroll
    for (int i = 0; i < 4; i++) {
        int row0 = bm + wr * 64 + i * 16 + lhi * 4;   // +r
        #pragma unroll
        for (int j = 0; j < 4; j++) {
            int col = bn + wc * 64 + j * 16 + l16;
            float bv = bias[col];
            if (EPI == 0) {
                #pragma unroll
                for (int r = 0; r < 4; r++)
                    Cf[(size_t)(row0 + r) * N + col] = acc[i][j][r] + bv;
            } else {
                int b_ = row0 >> 11;          // T = 2048
                int t0 = row0 & 2047;
                int s  = col >> 10;           // 0=Q 1=K 2=V
                int h  = (col >> 6) & 15;
                int d  = col & 63;
                int bh = b_ * 16 + h;
                if (s < 2) {
                    f16* dst = (s == 0 ? Qc : Kc);
                    #pragma unroll
                    for (int r = 0; r < 4; r++)
                        dst[((size_t)bh * Tq + t0 + r) * 64 + d] = (f16)(acc[i][j][r] + bv);
                } else {
                    f16x4 p;
                    #pragma unroll
                    for (int r = 0; r < 4; r++) p[r] = (f16)(acc[i][j][r] + bv);
                    *(f16x4*)&Vt[((size_t)bh * 64 + d) * Tq + t0] = p;
                }
            }
        }
    }
}

// ------------- attention: softmax(Q K^T) V / 8 -> Yc (f16, [b*T][C]) -------------
// Two-sided swap: QK^T = mfma(K, Q) (D col = q), PV = mfma(V, P^T) (D col = q).
// K staged at bit-permuted LDS rows so each lane's 16 P values are exactly its
// PV B-fragment slots -> P stays in-register (8 cvt_pkrtz, zero cross-lane ops).
__global__ __launch_bounds__(256) void k_attn(
    const f16* __restrict__ Qc, const f16* __restrict__ Kc, const f16* __restrict__ Vt,
    f16* __restrict__ Yc)
{
    __shared__ __align__(16) f16 Ks[64][64];
    __shared__ __align__(16) f16 Vs[64][64];

    const int tid = threadIdx.x;
    const int lane = tid & 63, wv = tid >> 6;
    const int l16 = lane & 15, lhi = lane >> 4;
    const int bh = blockIdx.y;
    const int q0 = blockIdx.x * 64;

    const f16* Qh = Qc + (size_t)bh * Tq * 64;
    const f16* Kh = Kc + (size_t)bh * Tq * 64;
    const f16* Vh = Vt + (size_t)bh * 64 * Tq;

    // staging geometry: thread covers rows {row0, row0+32}, 16B chunk ch0
    const int row0 = tid >> 3, ch0 = tid & 7;
    // K LDS row permutation: mem key bits (r4 r3 r2 r1 r0) -> LDS row (r2 r4 r3 r1 r0)
    // so that QK^T D rows enumerate keys as 32(ck>>1) + 8*lhi + 4(ck&1) + r,
    // matching the PV B-fragment slot order exactly.
    const int rp0  = (((row0 >> 2) & 1) << 4) | (((row0 >> 4) & 1) << 3)
                   | (((row0 >> 3) & 1) << 2) | (row0 & 3);
    const int pchK = ch0 ^ (rp0 & 7);           // rp0+32 has same low 3 bits
    const int pchV = ch0 ^ (row0 & 7);

    // Q fragments (B operand of QK^T): col = q = q0+wv*16+l16, k = kk*32+lhi*8
    f16x8 qf[2];
    {
        int qrow = q0 + wv * 16 + l16;
        #pragma unroll
        for (int kk = 0; kk < 2; kk++)
            qf[kk] = *(const f16x8*)(Qh + (size_t)qrow * 64 + kk * 32 + lhi * 8);
    }

    f32x4 o[4] = {};           // O[q = l16][d = ct*16 + lhi*4 + r]
    float m2 = -3e38f, l = 0.0f;  // per-lane softmax state for q = l16

    // prefetch tile 0
    f16x8 kr0, kr1, vr0, vr1;
    kr0 = *(const f16x8*)(Kh + (size_t)row0 * 64 + ch0 * 8);
    kr1 = *(const f16x8*)(Kh + (size_t)(row0 + 32) * 64 + ch0 * 8);
    vr0 = *(const f16x8*)(Vh + (size_t)row0 * Tq + ch0 * 8);
    vr1 = *(const f16x8*)(Vh + (size_t)(row0 + 32) * Tq + ch0 * 8);

    for (int t = 0; t < 32; t++) {
        __syncthreads();                       // prev compute done, LDS free
        *(f16x8*)&Ks[rp0][pchK * 8]       = kr0;
        *(f16x8*)&Ks[rp0 + 32][pchK * 8]  = kr1;
        *(f16x8*)&Vs[row0][pchV * 8]      = vr0;
        *(f16x8*)&Vs[row0 + 32][pchV * 8] = vr1;
        __syncthreads();                       // LDS ready
        if (t < 31) {                          // prefetch next tile (hides under compute)
            int kt2 = (t + 1) * 64;
            kr0 = *(const f16x8*)(Kh + (size_t)(kt2 + row0) * 64 + ch0 * 8);
            kr1 = *(const f16x8*)(Kh + (size_t)(kt2 + row0 + 32) * 64 + ch0 * 8);
            vr0 = *(const f16x8*)(Vh + (size_t)row0 * Tq + kt2 + ch0 * 8);
            vr1 = *(const f16x8*)(Vh + (size_t)(row0 + 32) * Tq + kt2 + ch0 * 8);
        }

        // S^T = K Q  (A = K from permuted LDS rows, B = Q)
        f32x4 s[4];
        #pragma unroll
        for (int ck = 0; ck < 4; ck++) {
            f32x4 acc = {};
            #pragma unroll
            for (int kk = 0; kk < 2; kk++) {
                f16x8 kf = *(const f16x8*)&Ks[ck * 16 + l16][((kk * 4 + lhi) ^ (l16 & 7)) * 8];
                acc = MFMA16(kf, qf[kk], acc);
            }
            s[ck] = acc;
        }
        // lane holds S[q=l16][mem key = 32(ck>>1) + 8*lhi + 4(ck&1) + r]

        // tile max for this lane's q (15 in-lane fmax + 2 shfl over lhi)
        float tm = fmaxf(
            fmaxf(fmaxf(fmaxf(s[0][0], s[0][1]), fmaxf(s[0][2], s[0][3])),
                  fmaxf(fmaxf(s[1][0], s[1][1]), fmaxf(s[1][2], s[1][3]))),
            fmaxf(fmaxf(fmaxf(s[2][0], s[2][1]), fmaxf(s[2][2], s[2][3])),
                  fmaxf(fmaxf(s[3][0], s[3][1]), fmaxf(s[3][2], s[3][3]))));
        tm = fmaxf(tm, __shfl_xor(tm, 16));
        tm = fmaxf(tm, __shfl_xor(tm, 32));

        // defer-max: rescale only when max grows by > 8 (P bounded by e^8 < f16 max)
        if (!__all(tm - m2 <= 8.0f)) {
            float mn = fmaxf(m2, tm);
            float sc = EXP2((m2 - mn) * LOG2E);
            m2 = mn; l *= sc;
            #pragma unroll
            for (int ct = 0; ct < 4; ct++)
                #pragma unroll
                for (int r = 0; r < 4; r++)
                    o[ct][r] *= sc;            // in-lane: o cols are this lane's q
        }

        // P = exp(s - m) via exp2(fma)
        float nm2 = -m2 * LOG2E;
        f32x4 p[4];
        #pragma unroll
        for (int ck = 0; ck < 4; ck++)
            #pragma unroll
            for (int r = 0; r < 4; r++)
                p[ck][r] = EXP2(fmaf(s[ck][r], LOG2E, nm2));

        // l += sum(P) (15 in-lane adds + 2 shfl)
        float su = ((p[0][0] + p[0][1]) + (p[0][2] + p[0][3]))
                 + ((p[1][0] + p[1][1]) + (p[1][2] + p[1][3]))
                 + ((p[2][0] + p[2][1]) + (p[2][2] + p[2][3]))
                 + ((p[3][0] + p[3][1]) + (p[3][2] + p[3][3]));
        su += __shfl_xor(su, 16);
        su += __shfl_xor(su, 32);
        l += su;

        // PV: O^T += V * P^T.  B-frag (P^T) is this lane's own p, packed:
        // slots j=0..7 of MFMA kk2 = (p[2kk2][0..3], p[2kk2+1][0..3])
        #pragma unroll
        for (int kk2 = 0; kk2 < 2; kk2++) {
            i32x4 w;
            w[0] = __builtin_bit_cast(int, __builtin_amdgcn_cvt_pkrtz(p[2*kk2][0],   p[2*kk2][1]));
            w[1] = __builtin_bit_cast(int, __builtin_amdgcn_cvt_pkrtz(p[2*kk2][2],   p[2*kk2][3]));
            w[2] = __builtin_bit_cast(int, __builtin_amdgcn_cvt_pkrtz(p[2*kk2+1][0], p[2*kk2+1][1]));
            w[3] = __builtin_bit_cast(int, __builtin_amdgcn_cvt_pkrtz(p[2*kk2+1][2], p[2*kk2+1][3]));
            f16x8 pb = __builtin_bit_cast(f16x8, w);
            #pragma unroll
            for (int ct = 0; ct < 4; ct++) {
                f16x8 vf = *(const f16x8*)&Vs[ct * 16 + l16][((kk2 * 4 + lhi) ^ (l16 & 7)) * 8];
                o[ct] = MFMA16(vf, pb, o[ct]);
            }
        }
    }

    // epilogue: y = o / l / 8; o[ct][r] = O[q=l16][d=ct*16+lhi*4+r] -> f16x4 stores
    const int b_ = bh >> 4, h_ = bh & 15;
    const int q  = q0 + wv * 16 + l16;
    const float inv = 1.0f / (l * 8.0f);
    size_t rb = (size_t)(b_ * Tq + q) * Cdim + h_ * 64;
    #pragma unroll
    for (int ct = 0; ct < 4; ct++) {
        f16x4 y;
        #pragma unroll
        for (int r = 0; r < 4; r++) y[r] = (f16)(o[ct][r] * inv);
        *(f16x4*)&Yc[rb + ct * 16 + lhi * 4] = y;
    }
}

extern "C" void kernel_launch(void* const* d_in, const int* in_sizes, int n_in,
                              void* d_out, int out_size, void* d_ws, size_t ws_size,
                              hipStream_t stream)
{
    (void)in_sizes; (void)n_in; (void)out_size; (void)ws_size;
    const float* x  = (const float*)d_in[0];
    const float* Wa = (const float*)d_in[1];
    const float* ba = (const float*)d_in[2];
    const float* Wp = (const float*)d_in[3];
    const float* bp = (const float*)d_in[4];
    float* out = (float*)d_out;

    char* ws = (char*)d_ws;               // needs 48 MB
    f16* Xh  = (f16*)(ws);                //  8 MB  [4096][1024]
    f16* WaT = (f16*)(ws + (8u  << 20));  //  6 MB  [3072][1024]
    f16* WpT = (f16*)(ws + (14u << 20));  //  2 MB  [1024][1024]
    f16* Qc  = (f16*)(ws + (16u << 20));  //  8 MB  [32][2048][64]
    f16* Kc  = (f16*)(ws + (24u << 20));  //  8 MB  [32][2048][64]
    f16* Vt  = (f16*)(ws + (32u << 20));  //  8 MB  [32][64][2048]
    f16* Yc  = (f16*)(ws + (40u << 20));  //  8 MB  [4096][1024]

    k_cvt_x<<<4096, 256, 0, stream>>>(x, Xh);
    k_trans<<<dim3(48, 16), 256, 0, stream>>>(Wa, WaT, 1024, 3072);
    k_trans<<<dim3(16, 16), 256, 0, stream>>>(Wp, WpT, 1024, 1024);
    k_gemm<1><<<dim3(24, 32), 256, 0, stream>>>(Xh, WaT, ba, nullptr, Qc, Kc, Vt, 3072, 1024);
    k_attn<<<dim3(32, 32), 256, 0, stream>>>(Qc, Kc, Vt, Yc);
    k_gemm<0><<<dim3(8, 32), 256, 0, stream>>>(Yc, WpT, bp, out, nullptr, nullptr, nullptr, 1024, 1024);
}

// Round 6
// 213.341 us; speedup vs baseline: 1.2533x; 1.0178x over previous
//
#include <hip/hip_runtime.h>

typedef _Float16 f16;
typedef f16  f16x8 __attribute__((ext_vector_type(8)));
typedef f16  f16x4 __attribute__((ext_vector_type(4)));
typedef float f32x4 __attribute__((ext_vector_type(4)));
typedef int  i32x4 __attribute__((ext_vector_type(4)));

#define MFMA16(a,b,c) __builtin_amdgcn_mfma_f32_16x16x32_f16((a),(b),(c),0,0,0)
#define EXP2(x) __builtin_amdgcn_exp2f(x)
#define LOG2E 1.44269504089f

static constexpr int Tq   = 2048;  // sequence length
static constexpr int Cdim = 1024;  // model dim
// heads = 16, d_head = 64, batch = 2 (hardcoded below)

// async global->LDS, 16B per lane; dest is wave-uniform base + lane*16
__device__ static inline void gload_lds16(const f16* gsrc, f16* ldst)
{
    __builtin_amdgcn_global_load_lds(
        (const __attribute__((address_space(1))) void*)gsrc,
        (__attribute__((address_space(3))) void*)ldst, 16, 0, 0);
}

// ---------------- x (f32) -> f16 ----------------
__global__ __launch_bounds__(256) void k_cvt_x(const float* __restrict__ x, f16* __restrict__ xh)
{
    int i = blockIdx.x * 256 + threadIdx.x;
    f32x4 v = ((const f32x4*)x)[i];
    f16x4 o; o[0] = (f16)v[0]; o[1] = (f16)v[1]; o[2] = (f16)v[2]; o[3] = (f16)v[3];
    ((f16x4*)xh)[i] = o;
}

// ------------- W (K x N, f32) -> WT (N x K, f16) -------------
__global__ __launch_bounds__(256) void k_trans(const float* __restrict__ W, f16* __restrict__ WT,
                                               int K, int N)
{
    __shared__ float t[64][65];
    int n0 = blockIdx.x * 64, k0 = blockIdx.y * 64;
    int tid = threadIdx.x;
    int lr = tid >> 6, lc = tid & 63;
    #pragma unroll 4
    for (int i = 0; i < 16; i++) {
        int kl = lr * 16 + i;
        t[kl][lc] = W[(size_t)(k0 + kl) * N + n0 + lc];
    }
    __syncthreads();
    #pragma unroll 4
    for (int i = 0; i < 16; i++) {
        int nl = lr * 16 + i;
        WT[(size_t)(n0 + nl) * K + k0 + lc] = (f16)t[lc][nl];
    }
}

// ------------- GEMM: C = A(MxK) * BT(NxK)^T + bias -------------
// m97 structure: global_load_lds(16B) staging, linear LDS dest, pre-swizzled
// global source (chunk ch = pch ^ (row&7)), 2 barriers per K-step.
// EPI 0: write f32 C.  EPI 1: route QKV into Qc/Kc (bh,t,d) and Vt (bh,d,t).
template<int EPI>
__global__ __launch_bounds__(256) void k_gemm(
    const f16* __restrict__ A, const f16* __restrict__ BT, const float* __restrict__ bias,
    float* __restrict__ Cf, f16* __restrict__ Qc, f16* __restrict__ Kc, f16* __restrict__ Vt,
    int N, int K)
{
    __shared__ __align__(16) f16 As[128][64];
    __shared__ __align__(16) f16 Bs[128][64];
    const int tid = threadIdx.x;
    const int lane = tid & 63, wv = tid >> 6;
    const int l16 = lane & 15, lhi = lane >> 4;
    const int wr = wv >> 1, wc = wv & 1;
    const int bm = blockIdx.y * 128, bn = blockIdx.x * 128;

    // staging geometry: issue i of wave wv covers 8 rows starting at blk*8.
    // Lane l -> row blk*8 + (l>>3), LDS chunk l&7 (linear); global chunk
    // ch = (l&7) ^ (row&7) so that LDS slot pch holds global chunk pch^(row&7).
    const int srow = lane >> 3;                 // 0..7 within an issue block
    const int sch  = (lane & 7) ^ (srow & 7);   // pre-swizzled global chunk

    f32x4 acc[4][4] = {};

    for (int kt = 0; kt < K; kt += 64) {
        #pragma unroll
        for (int i = 0; i < 4; i++) {
            int blk = wv * 4 + i;               // 16 blocks of 8 rows
            int row = blk * 8 + srow;
            gload_lds16(A  + (size_t)(bm + row) * K + kt + sch * 8, &As[blk * 8][0]);
            gload_lds16(BT + (size_t)(bn + row) * K + kt + sch * 8, &Bs[blk * 8][0]);
        }
        __syncthreads();                        // drains vmcnt(0): tiles ready
        #pragma unroll
        for (int kk = 0; kk < 2; kk++) {
            f16x8 af[4], bfr[4];
            #pragma unroll
            for (int i = 0; i < 4; i++) {
                int ra = wr * 64 + i * 16 + l16;
                af[i]  = *(const f16x8*)&As[ra][((kk * 4 + lhi) ^ (ra & 7)) * 8];
                int rb = wc * 64 + i * 16 + l16;
                bfr[i] = *(const f16x8*)&Bs[rb][((kk * 4 + lhi) ^ (rb & 7)) * 8];
            }
            #pragma unroll
            for (int i = 0; i < 4; i++)
                #pragma unroll
                for (int j = 0; j < 4; j++)
                    acc[i][j] = MFMA16(af[i], bfr[j], acc[i][j]);
        }
        __syncthreads();                        // all waves done reading LDS
    }

    #pragma unroll
    for (int i = 0; i < 4; i++) {
        int row0 = bm + wr * 64 + i * 16 + lhi * 4;   // +r
        #pragma unroll
        for (int j = 0; j < 4; j++) {
            int col = bn + wc * 64 + j * 16 + l16;
            float bv = bias[col];
            if (EPI == 0) {
                #pragma unroll
                for (int r = 0; r < 4; r++)
                    Cf[(size_t)(row0 + r) * N + col] = acc[i][j][r] + bv;
            } else {
                int b_ = row0 >> 11;          // T = 2048
                int t0 = row0 & 2047;
                int s  = col >> 10;           // 0=Q 1=K 2=V
                int h  = (col >> 6) & 15;
                int d  = col & 63;
                int bh = b_ * 16 + h;
                if (s < 2) {
                    f16* dst = (s == 0 ? Qc : Kc);
                    #pragma unroll
                    for (int r = 0; r < 4; r++)
                        dst[((size_t)bh * Tq + t0 + r) * 64 + d] = (f16)(acc[i][j][r] + bv);
                } else {
                    f16x4 p;
                    #pragma unroll
                    for (int r = 0; r < 4; r++) p[r] = (f16)(acc[i][j][r] + bv);
                    *(f16x4*)&Vt[((size_t)bh * 64 + d) * Tq + t0] = p;
                }
            }
        }
    }
}

// ------------- attention: softmax(Q K^T) V / 8 -> Yc (f16, [b*T][C]) -------------
// Two-sided swap: QK^T = mfma(K, Q) (D col = q), PV = mfma(V, P^T) (D col = q).
// K staged at bit-permuted LDS rows so each lane's 16 P values are exactly its
// PV B-fragment slots -> P stays in-register (8 cvt_pkrtz, zero cross-lane ops).
__global__ __launch_bounds__(256) void k_attn(
    const f16* __restrict__ Qc, const f16* __restrict__ Kc, const f16* __restrict__ Vt,
    f16* __restrict__ Yc)
{
    __shared__ __align__(16) f16 Ks[64][64];
    __shared__ __align__(16) f16 Vs[64][64];

    const int tid = threadIdx.x;
    const int lane = tid & 63, wv = tid >> 6;
    const int l16 = lane & 15, lhi = lane >> 4;
    const int bh = blockIdx.y;
    const int q0 = blockIdx.x * 64;

    const f16* Qh = Qc + (size_t)bh * Tq * 64;
    const f16* Kh = Kc + (size_t)bh * Tq * 64;
    const f16* Vh = Vt + (size_t)bh * 64 * Tq;

    // staging geometry: thread covers rows {row0, row0+32}, 16B chunk ch0
    const int row0 = tid >> 3, ch0 = tid & 7;
    // K LDS row permutation: mem key bits (r4 r3 r2 r1 r0) -> LDS row (r2 r4 r3 r1 r0)
    // so that QK^T D rows enumerate keys as 32(ck>>1) + 8*lhi + 4(ck&1) + r,
    // matching the PV B-fragment slot order exactly.
    const int rp0  = (((row0 >> 2) & 1) << 4) | (((row0 >> 4) & 1) << 3)
                   | (((row0 >> 3) & 1) << 2) | (row0 & 3);
    const int pchK = ch0 ^ (rp0 & 7);           // rp0+32 has same low 3 bits
    const int pchV = ch0 ^ (row0 & 7);

    // Q fragments (B operand of QK^T): col = q = q0+wv*16+l16, k = kk*32+lhi*8
    f16x8 qf[2];
    {
        int qrow = q0 + wv * 16 + l16;
        #pragma unroll
        for (int kk = 0; kk < 2; kk++)
            qf[kk] = *(const f16x8*)(Qh + (size_t)qrow * 64 + kk * 32 + lhi * 8);
    }

    f32x4 o[4] = {};           // O[q = l16][d = ct*16 + lhi*4 + r]
    float m2 = -3e38f, l = 0.0f;  // per-lane softmax state for q = l16

    // prefetch tile 0
    f16x8 kr0, kr1, vr0, vr1;
    kr0 = *(const f16x8*)(Kh + (size_t)row0 * 64 + ch0 * 8);
    kr1 = *(const f16x8*)(Kh + (size_t)(row0 + 32) * 64 + ch0 * 8);
    vr0 = *(const f16x8*)(Vh + (size_t)row0 * Tq + ch0 * 8);
    vr1 = *(const f16x8*)(Vh + (size_t)(row0 + 32) * Tq + ch0 * 8);

    for (int t = 0; t < 32; t++) {
        __syncthreads();                       // prev compute done, LDS free
        *(f16x8*)&Ks[rp0][pchK * 8]       = kr0;
        *(f16x8*)&Ks[rp0 + 32][pchK * 8]  = kr1;
        *(f16x8*)&Vs[row0][pchV * 8]      = vr0;
        *(f16x8*)&Vs[row0 + 32][pchV * 8] = vr1;
        __syncthreads();                       // LDS ready
        if (t < 31) {                          // prefetch next tile (hides under compute)
            int kt2 = (t + 1) * 64;
            kr0 = *(const f16x8*)(Kh + (size_t)(kt2 + row0) * 64 + ch0 * 8);
            kr1 = *(const f16x8*)(Kh + (size_t)(kt2 + row0 + 32) * 64 + ch0 * 8);
            vr0 = *(const f16x8*)(Vh + (size_t)row0 * Tq + kt2 + ch0 * 8);
            vr1 = *(const f16x8*)(Vh + (size_t)(row0 + 32) * Tq + kt2 + ch0 * 8);
        }

        // S^T = K Q  (A = K from permuted LDS rows, B = Q)
        f32x4 s[4];
        #pragma unroll
        for (int ck = 0; ck < 4; ck++) {
            f32x4 acc = {};
            #pragma unroll
            for (int kk = 0; kk < 2; kk++) {
                f16x8 kf = *(const f16x8*)&Ks[ck * 16 + l16][((kk * 4 + lhi) ^ (l16 & 7)) * 8];
                acc = MFMA16(kf, qf[kk], acc);
            }
            s[ck] = acc;
        }
        // lane holds S[q=l16][mem key = 32(ck>>1) + 8*lhi + 4(ck&1) + r]

        // tile max for this lane's q (15 in-lane fmax + 2 shfl over lhi)
        float tm = fmaxf(
            fmaxf(fmaxf(fmaxf(s[0][0], s[0][1]), fmaxf(s[0][2], s[0][3])),
                  fmaxf(fmaxf(s[1][0], s[1][1]), fmaxf(s[1][2], s[1][3]))),
            fmaxf(fmaxf(fmaxf(s[2][0], s[2][1]), fmaxf(s[2][2], s[2][3])),
                  fmaxf(fmaxf(s[3][0], s[3][1]), fmaxf(s[3][2], s[3][3]))));
        tm = fmaxf(tm, __shfl_xor(tm, 16));
        tm = fmaxf(tm, __shfl_xor(tm, 32));

        // defer-max: rescale only when max grows by > 8 (P bounded by e^8 < f16 max)
        if (!__all(tm - m2 <= 8.0f)) {
            float mn = fmaxf(m2, tm);
            float sc = EXP2((m2 - mn) * LOG2E);
            m2 = mn; l *= sc;
            #pragma unroll
            for (int ct = 0; ct < 4; ct++)
                #pragma unroll
                for (int r = 0; r < 4; r++)
                    o[ct][r] *= sc;            // in-lane: o cols are this lane's q
        }

        // P = exp(s - m) via exp2(fma)
        float nm2 = -m2 * LOG2E;
        f32x4 p[4];
        #pragma unroll
        for (int ck = 0; ck < 4; ck++)
            #pragma unroll
            for (int r = 0; r < 4; r++)
                p[ck][r] = EXP2(fmaf(s[ck][r], LOG2E, nm2));

        // l += sum(P) (15 in-lane adds + 2 shfl)
        float su = ((p[0][0] + p[0][1]) + (p[0][2] + p[0][3]))
                 + ((p[1][0] + p[1][1]) + (p[1][2] + p[1][3]))
                 + ((p[2][0] + p[2][1]) + (p[2][2] + p[2][3]))
                 + ((p[3][0] + p[3][1]) + (p[3][2] + p[3][3]));
        su += __shfl_xor(su, 16);
        su += __shfl_xor(su, 32);
        l += su;

        // PV: O^T += V * P^T.  B-frag (P^T) is this lane's own p, packed:
        // slots j=0..7 of MFMA kk2 = (p[2kk2][0..3], p[2kk2+1][0..3])
        #pragma unroll
        for (int kk2 = 0; kk2 < 2; kk2++) {
            i32x4 w;
            w[0] = __builtin_bit_cast(int, __builtin_amdgcn_cvt_pkrtz(p[2*kk2][0],   p[2*kk2][1]));
            w[1] = __builtin_bit_cast(int, __builtin_amdgcn_cvt_pkrtz(p[2*kk2][2],   p[2*kk2][3]));
            w[2] = __builtin_bit_cast(int, __builtin_amdgcn_cvt_pkrtz(p[2*kk2+1][0], p[2*kk2+1][1]));
            w[3] = __builtin_bit_cast(int, __builtin_amdgcn_cvt_pkrtz(p[2*kk2+1][2], p[2*kk2+1][3]));
            f16x8 pb = __builtin_bit_cast(f16x8, w);
            #pragma unroll
            for (int ct = 0; ct < 4; ct++) {
                f16x8 vf = *(const f16x8*)&Vs[ct * 16 + l16][((kk2 * 4 + lhi) ^ (l16 & 7)) * 8];
                o[ct] = MFMA16(vf, pb, o[ct]);
            }
        }
    }

    // epilogue: y = o / l / 8; o[ct][r] = O[q=l16][d=ct*16+lhi*4+r] -> f16x4 stores
    const int b_ = bh >> 4, h_ = bh & 15;
    const int q  = q0 + wv * 16 + l16;
    const float inv = 1.0f / (l * 8.0f);
    size_t rb = (size_t)(b_ * Tq + q) * Cdim + h_ * 64;
    #pragma unroll
    for (int ct = 0; ct < 4; ct++) {
        f16x4 y;
        #pragma unroll
        for (int r = 0; r < 4; r++) y[r] = (f16)(o[ct][r] * inv);
        *(f16x4*)&Yc[rb + ct * 16 + lhi * 4] = y;
    }
}

extern "C" void kernel_launch(void* const* d_in, const int* in_sizes, int n_in,
                              void* d_out, int out_size, void* d_ws, size_t ws_size,
                              hipStream_t stream)
{
    (void)in_sizes; (void)n_in; (void)out_size; (void)ws_size;
    const float* x  = (const float*)d_in[0];
    const float* Wa = (const float*)d_in[1];
    const float* ba = (const float*)d_in[2];
    const float* Wp = (const float*)d_in[3];
    const float* bp = (const float*)d_in[4];
    float* out = (float*)d_out;

    char* ws = (char*)d_ws;               // needs 48 MB
    f16* Xh  = (f16*)(ws);                //  8 MB  [4096][1024]
    f16* WaT = (f16*)(ws + (8u  << 20));  //  6 MB  [3072][1024]
    f16* WpT = (f16*)(ws + (14u << 20));  //  2 MB  [1024][1024]
    f16* Qc  = (f16*)(ws + (16u << 20));  //  8 MB  [32][2048][64]
    f16* Kc  = (f16*)(ws + (24u << 20));  //  8 MB  [32][2048][64]
    f16* Vt  = (f16*)(ws + (32u << 20));  //  8 MB  [32][64][2048]
    f16* Yc  = (f16*)(ws + (40u << 20));  //  8 MB  [4096][1024]

    k_cvt_x<<<4096, 256, 0, stream>>>(x, Xh);
    k_trans<<<dim3(48, 16), 256, 0, stream>>>(Wa, WaT, 1024, 3072);
    k_trans<<<dim3(16, 16), 256, 0, stream>>>(Wp, WpT, 1024, 1024);
    k_gemm<1><<<dim3(24, 32), 256, 0, stream>>>(Xh, WaT, ba, nullptr, Qc, Kc, Vt, 3072, 1024);
    k_attn<<<dim3(32, 32), 256, 0, stream>>>(Qc, Kc, Vt, Yc);
    k_gemm<0><<<dim3(8, 32), 256, 0, stream>>>(Yc, WpT, bp, out, nullptr, nullptr, nullptr, 1024, 1024);
}